// Round 1
// baseline (197.996 us; speedup 1.0000x reference)
//
#include <hip/hip_runtime.h>

#define NL 30

// Packed fp32 pair: 2 rows per register pair -> v_pk_fma_f32 (full-rate on CDNA4).
typedef float v2f __attribute__((ext_vector_type(2)));

static __device__ __forceinline__ v2f vsplat(float x) { v2f r; r.x = x; r.y = x; return r; }
static __device__ __forceinline__ v2f vrelu(v2f a) {
    // No v_pk_max_f32 on gfx950: 2x v_max_f32, unavoidable scalar part.
    v2f r; r.x = fmaxf(a.x, 0.f); r.y = fmaxf(a.y, 0.f); return r;
}
static __device__ __forceinline__ v2f vfma(v2f a, v2f b, v2f c) {
    return __builtin_elementwise_fma(a, b, c);   // <2 x float> llvm.fma -> v_pk_fma_f32
}

// 4 rows per thread:
//  - x2/o2 become 5x float4 (16B-aligned, fully coalesced) instead of 5 strided dwords/row
//  - all fma/add work runs as packed-f32 on row pairs (a = rows 0,1; b = rows 2,3)
//  - params read with uniform (compile-time) indices in a fully unrolled layer loop
//    -> s_load into SGPRs on the scalar pipe; no LDS, no __syncthreads, no ds_read issue.
__global__ __launch_bounds__(256) void drn_kernel(
    const float* __restrict__ x1, const float* __restrict__ x2,
    const float* __restrict__ W1, const float* __restrict__ b1,
    const float* __restrict__ W2,
    float* __restrict__ o1, float* __restrict__ o2)
{
    const int tid = blockIdx.x * 256 + threadIdx.x;   // rows 4*tid .. 4*tid+3

    const float4 a1 = ((const float4*)x1)[tid];
    v2f h1a = {a1.x, a1.y};
    v2f h1b = {a1.z, a1.w};

    const float4* x2v = (const float4*)x2 + tid * 5;  // 80B/thread, 16B aligned
    float4 q0 = x2v[0], q1 = x2v[1], q2 = x2v[2], q3 = x2v[3], q4 = x2v[4];
    const float r[20] = {q0.x,q0.y,q0.z,q0.w, q1.x,q1.y,q1.z,q1.w,
                         q2.x,q2.y,q2.z,q2.w, q3.x,q3.y,q3.z,q3.w,
                         q4.x,q4.y,q4.z,q4.w};
    v2f h2a[5], h2b[5];
    #pragma unroll
    for (int j = 0; j < 5; ++j) {
        h2a[j].x = r[j];      h2a[j].y = r[5 + j];
        h2b[j].x = r[10 + j]; h2b[j].y = r[15 + j];
    }

    #pragma unroll
    for (int l = 0; l < NL; ++l) {
        // Uniform loads -> SGPRs. Splats (shared by both row pairs) cost at most
        // 11 v_mov per layer per THREAD (2.75/row), or 0 if op_sel broadcast folds.
        const v2f vw1[5] = {vsplat(W1[l*5+0]), vsplat(W1[l*5+1]), vsplat(W1[l*5+2]),
                            vsplat(W1[l*5+3]), vsplat(W1[l*5+4])};
        const v2f vbb  = vsplat(b1[l]);
        const v2f vw2[5] = {vsplat(W2[l*5+0]), vsplat(W2[l*5+1]), vsplat(W2[l*5+2]),
                            vsplat(W2[l*5+3]), vsplat(W2[l*5+4])};

        // rows 0,1
        {
            v2f s = h1a + vbb;
            #pragma unroll
            for (int j = 0; j < 5; ++j) s = vfma(vrelu(h2a[j]), vw1[j], s);
            h1a = s;
            const v2f rh = vrelu(s);
            #pragma unroll
            for (int j = 0; j < 5; ++j) h2a[j] = vfma(rh, vw2[j], h2a[j]);
        }
        // rows 2,3
        {
            v2f s = h1b + vbb;
            #pragma unroll
            for (int j = 0; j < 5; ++j) s = vfma(vrelu(h2b[j]), vw1[j], s);
            h1b = s;
            const v2f rh = vrelu(s);
            #pragma unroll
            for (int j = 0; j < 5; ++j) h2b[j] = vfma(rh, vw2[j], h2b[j]);
        }
    }

    ((float4*)o1)[tid] = make_float4(h1a.x, h1a.y, h1b.x, h1b.y);

    float w[20];
    #pragma unroll
    for (int j = 0; j < 5; ++j) {
        w[j]      = h2a[j].x;  w[5 + j]  = h2a[j].y;
        w[10 + j] = h2b[j].x;  w[15 + j] = h2b[j].y;
    }
    float4* o2v = (float4*)o2 + tid * 5;
    o2v[0] = make_float4(w[0],  w[1],  w[2],  w[3]);
    o2v[1] = make_float4(w[4],  w[5],  w[6],  w[7]);
    o2v[2] = make_float4(w[8],  w[9],  w[10], w[11]);
    o2v[3] = make_float4(w[12], w[13], w[14], w[15]);
    o2v[4] = make_float4(w[16], w[17], w[18], w[19]);
}

extern "C" void kernel_launch(void* const* d_in, const int* in_sizes, int n_in,
                              void* d_out, int out_size, void* d_ws, size_t ws_size,
                              hipStream_t stream) {
    const float* x1 = (const float*)d_in[0];
    const float* x2 = (const float*)d_in[1];
    const float* W1 = (const float*)d_in[2];
    const float* b1 = (const float*)d_in[3];
    const float* W2 = (const float*)d_in[4];
    int nrows = in_sizes[0];            // 4,194,304 = 4096 * 1024
    float* o1 = (float*)d_out;          // [nrows]
    float* o2 = (float*)d_out + nrows;  // [nrows*5]

    int block = 256;
    int grid = nrows / (block * 4);     // 4096 blocks, 4 rows/thread
    drn_kernel<<<grid, block, 0, stream>>>(x1, x2, W1, b1, W2, o1, o2);
}

// Round 3
// 192.924 us; speedup vs baseline: 1.0263x; 1.0263x over previous
//
#include <hip/hip_runtime.h>

#define NL 30

// Packed fp32: 2 rows per register pair -> v_pk_fma_f32/v_pk_add_f32 (full rate on CDNA4).
typedef float v2f __attribute__((ext_vector_type(2)));

static __device__ __forceinline__ v2f flo(float4 v) { v2f r; r.x = v.x; r.y = v.y; return r; }
static __device__ __forceinline__ v2f fhi(float4 v) { v2f r; r.x = v.z; r.y = v.w; return r; }
static __device__ __forceinline__ v2f vrelu(v2f a) {
    // no v_pk_max_f32 on gfx950 -> 2x v_max_f32 (inline-const 0, 1 instr each)
    v2f r; r.x = fmaxf(a.x, 0.f); r.y = fmaxf(a.y, 0.f); return r;
}
static __device__ __forceinline__ v2f vfma(v2f a, v2f b, v2f c) {
    return __builtin_elementwise_fma(a, b, c);   // -> v_pk_fma_f32
}

// R0 proved: LDS-broadcast params sustain high VALUBusy, 0 bank conflicts.
// R1 proved: packed f32 halves FMA issue count, but per-layer s_load splats stall.
// R2: weights stored PRE-DUPLICATED in LDS ({w,w} 8B pairs). One ds_read_b128
// yields two ready packed operands: no s_loads in the loop, no splat movs.
// Layout per layer (96B stride, 16B aligned): 6x float4 =
//   {w1_0,w1_0,w1_1,w1_1} {w1_2,w1_2,w1_3,w1_3} {w1_4,w1_4,b,b}
//   {w2_0,w2_0,w2_1,w2_1} {w2_2,w2_2,w2_3,w2_3} {w2_4,w2_4,pad,pad}
__global__ __launch_bounds__(256) void drn_kernel(
    const float* __restrict__ x1, const float* __restrict__ x2,
    const float* __restrict__ W1, const float* __restrict__ b1,
    const float* __restrict__ W2,
    float* __restrict__ o1, float* __restrict__ o2)
{
    __shared__ __align__(16) float sp[NL * 24];
    for (int i = threadIdx.x; i < NL * 24; i += 256) {
        int p = i >> 1, l = p / 12, k = p % 12;   // each pair written twice (i and i^1)
        float v = 0.0f;
        if (k < 5)        v = W1[l * 5 + k];
        else if (k == 5)  v = b1[l];
        else if (k < 11)  v = W2[l * 5 + (k - 6)];
        sp[i] = v;
    }
    __syncthreads();

    const int tid = blockIdx.x * 256 + threadIdx.x;   // rows 4*tid .. 4*tid+3

    const float4 a1 = ((const float4*)x1)[tid];
    v2f h1a = {a1.x, a1.y};
    v2f h1b = {a1.z, a1.w};

    const float4* x2v = (const float4*)x2 + tid * 5;  // 80B/thread, 16B aligned
    float4 q0 = x2v[0], q1 = x2v[1], q2 = x2v[2], q3 = x2v[3], q4 = x2v[4];
    const float r[20] = {q0.x,q0.y,q0.z,q0.w, q1.x,q1.y,q1.z,q1.w,
                         q2.x,q2.y,q2.z,q2.w, q3.x,q3.y,q3.z,q3.w,
                         q4.x,q4.y,q4.z,q4.w};
    v2f h2a[5], h2b[5];
    #pragma unroll
    for (int j = 0; j < 5; ++j) {
        h2a[j].x = r[j];      h2a[j].y = r[5 + j];
        h2b[j].x = r[10 + j]; h2b[j].y = r[15 + j];
    }

    const float4* spv = (const float4*)sp;
    #pragma unroll
    for (int l = 0; l < NL; ++l) {
        // 6x ds_read_b128, wave-uniform address -> broadcast, conflict-free.
        const float4 L0 = spv[l * 6 + 0];
        const float4 L1 = spv[l * 6 + 1];
        const float4 L2 = spv[l * 6 + 2];
        const float4 L3 = spv[l * 6 + 3];
        const float4 L4 = spv[l * 6 + 4];
        const float4 L5 = spv[l * 6 + 5];
        const v2f w10 = flo(L0), w11 = fhi(L0), w12 = flo(L1), w13 = fhi(L1),
                  w14 = flo(L2), vbb = fhi(L2),
                  w20 = flo(L3), w21 = fhi(L3), w22 = flo(L4), w23 = fhi(L4),
                  w24 = flo(L5);

        // rows 0,1
        {
            v2f s = h1a + vbb;
            s = vfma(vrelu(h2a[0]), w10, s);
            s = vfma(vrelu(h2a[1]), w11, s);
            s = vfma(vrelu(h2a[2]), w12, s);
            s = vfma(vrelu(h2a[3]), w13, s);
            s = vfma(vrelu(h2a[4]), w14, s);
            h1a = s;
            const v2f rh = vrelu(s);
            h2a[0] = vfma(rh, w20, h2a[0]);
            h2a[1] = vfma(rh, w21, h2a[1]);
            h2a[2] = vfma(rh, w22, h2a[2]);
            h2a[3] = vfma(rh, w23, h2a[3]);
            h2a[4] = vfma(rh, w24, h2a[4]);
        }
        // rows 2,3
        {
            v2f s = h1b + vbb;
            s = vfma(vrelu(h2b[0]), w10, s);
            s = vfma(vrelu(h2b[1]), w11, s);
            s = vfma(vrelu(h2b[2]), w12, s);
            s = vfma(vrelu(h2b[3]), w13, s);
            s = vfma(vrelu(h2b[4]), w14, s);
            h1b = s;
            const v2f rh = vrelu(s);
            h2b[0] = vfma(rh, w20, h2b[0]);
            h2b[1] = vfma(rh, w21, h2b[1]);
            h2b[2] = vfma(rh, w22, h2b[2]);
            h2b[3] = vfma(rh, w23, h2b[3]);
            h2b[4] = vfma(rh, w24, h2b[4]);
        }
    }

    ((float4*)o1)[tid] = make_float4(h1a.x, h1a.y, h1b.x, h1b.y);

    float w[20];
    #pragma unroll
    for (int j = 0; j < 5; ++j) {
        w[j]      = h2a[j].x;  w[5 + j]  = h2a[j].y;
        w[10 + j] = h2b[j].x;  w[15 + j] = h2b[j].y;
    }
    float4* o2v = (float4*)o2 + tid * 5;
    o2v[0] = make_float4(w[0],  w[1],  w[2],  w[3]);
    o2v[1] = make_float4(w[4],  w[5],  w[6],  w[7]);
    o2v[2] = make_float4(w[8],  w[9],  w[10], w[11]);
    o2v[3] = make_float4(w[12], w[13], w[14], w[15]);
    o2v[4] = make_float4(w[16], w[17], w[18], w[19]);
}

extern "C" void kernel_launch(void* const* d_in, const int* in_sizes, int n_in,
                              void* d_out, int out_size, void* d_ws, size_t ws_size,
                              hipStream_t stream) {
    const float* x1 = (const float*)d_in[0];
    const float* x2 = (const float*)d_in[1];
    const float* W1 = (const float*)d_in[2];
    const float* b1 = (const float*)d_in[3];
    const float* W2 = (const float*)d_in[4];
    int nrows = in_sizes[0];            // 4,194,304 = 4096 * 1024
    float* o1 = (float*)d_out;          // [nrows]
    float* o2 = (float*)d_out + nrows;  // [nrows*5]

    int block = 256;
    int grid = nrows / (block * 4);     // 4096 blocks, 4 rows/thread
    drn_kernel<<<grid, block, 0, stream>>>(x1, x2, W1, b1, W2, o1, o2);
}